// Round 14
// baseline (1110.057 us; speedup 1.0000x reference)
//
#include <hip/hip_runtime.h>
#include <cstddef>

// NLM: h=7/255, template 7x7 (TH=3), search 21x21 (SH=10), reflect padding.
// Tile 32x32/block, 256 threads, disjoint wave roles, ONE barrier per round.
// R15 = R14 + SYMMETRIC OFFSET-PAIR ROUNDS with float2-packed vsh:
//   Per oy row: 10 pair-rounds (ox=2k,2k+1 computed together; reads are
//   xs[a], xs[a+1] -> v_pk_*_f32 math) + 1 scalar round (ox=20) = 231
//   rounds (vs 441). One float2 buffer slot serves both offsets: Bv writes
//   11 b64 (vs 22 b32 / 2 offsets), C reads 14 b64 feeding BOTH h-chains
//   (vs 28 b32), barriers 441 -> 232, loop/addr overhead halved.
//   WHY: R14 accounting shows ~90% of SIMD issue bandwidth consumed
//   (VALU 74.5% + DS issues ~15%); this cuts VALU (pk), DS issues, and
//   barriers at once. Rounds stay symmetric (R12's asymmetric heavy/light
//   convoyed; occupancy counter reads ACTIVE waves).
//   Per-offset arithmetic order bit-identical (pk halves exact f32).
// R9 exact exp-block skip kept, per sub-offset (exp2 underflow -> +0.0).
// Lessons: no inner unroll of round loop (R2); 114-lane Bv (R5/R6); no fp16
// (R7); symmetric rounds (R12); 32x32 tile (R13); transposed vsh (R14).

typedef float v2f __attribute__((ext_vector_type(2)));

constexpr int TS    = 32;
constexpr int XSTR  = 61;            // odd -> benign bank aliasing
constexpr int XROWS = 59;            // image rows gy0-13 .. gy0+45
constexpr int XSZ   = XROWS * XSTR;  // 3599
constexpr int VT    = 33;            // slots per column (32 real + 1 junk)
constexpr int VCOLS = 38;
constexpr int VS_SZ = VCOLS * VT;    // 1254 float2 elements per buffer

__device__ __forceinline__ int refl(int i, int n) {
    i = (i < 0) ? -i : i;
    return (i >= n) ? (2 * n - 2 - i) : i;
}

template<bool FAST>
__device__ __forceinline__ void nlm_body(const float* __restrict__ img,
                                         float* __restrict__ out,
                                         int H, int W, int gx0, int gy0,
                                         float* __restrict__ xs,
                                         v2f* __restrict__ vsh, int tid)
{
    // ---- load xs (clip to [0,1], reflect indexing) ----
    for (int e = tid; e < XSZ; e += 256) {
        int i = e / XSTR, j = e - i * XSTR;
        int jj = (j > 57) ? 57 : j;  // cols 58..60: stride pad (never read)
        int gy = refl(gy0 - 13 + i, H);
        int gx = refl(gx0 - 13 + jj, W);
        float v = img[(size_t)gy * W + gx];
        xs[e] = fminf(fmaxf(v, 0.0f), 1.0f);
    }
    __syncthreads();

    // ---- Bv setup: 114 lanes = 38 cols x 3 row-groups (11 rows, 17 q's) ----
    const bool bv = (tid < 114);
    float u[17];
    int   aB = 0;                    // FAST: single address, +i*XSTR rows
    int   aS[17];                    // EDGE: per-row reflected addresses
    int   wb = 0;                    // vsh element index: cc*VT + r
    {
        int t  = bv ? tid : 0;
        int g  = t / 38;
        int cc = t - g * 38;
        int r  = g * 11;
        int mxm10 = refl(gx0 + cc - 3, W) - gx0 + 3;
        if constexpr (FAST) {
            aB = r * XSTR + mxm10;
#pragma unroll
            for (int i = 0; i < 17; ++i)
                u[i] = xs[(r + i + 10) * XSTR + mxm10 + 10];
        } else {
#pragma unroll
            for (int i = 0; i < 17; ++i) {
                int my = refl(gy0 + r + i - 3, H) - gy0 + 13;
                u[i]  = xs[my * XSTR + mxm10 + 10];
                aS[i] = (my - 10) * XSTR + mxm10;
            }
        }
        wb = cc * VT + r;
    }

    // ---- C setup: 128 lanes = 32 rows x 4 groups of 8 cols ----
    const bool cact = (tid >= 128);
    const int ct = cact ? (tid - 128) : 0;
    const int py = ct >> 2;
    const int c8 = (ct & 3) * 8;
    const int vb = c8 * VT + py;                // element base (transposed)
    int svC = (py + 3) * XSTR + (c8 + 3);       // row base, advances per oy
    int oxC = 0;

    float ws[8], ac[8];
#pragma unroll
    for (int k = 0; k < 8; ++k) { ws[k] = 0.f; ac[k] = 0.f; }
    const float K = -(65025.0f / 2401.0f) * 1.4426950408889634f;  // ~ -39.07
    const float HSKIP = 3.95f;  // h > 3.95 => h*K <= -154 => exp2 == +0.0f

    // pair round: offsets (ox, ox+1) packed as float2; write one slot set.
    auto bv_pair = [&](int buf) {
        if (bv) {
            v2f* vo = vsh + buf * VS_SZ + wb;
            v2f q[17];
#pragma unroll
            for (int i = 0; i < 17; ++i) {
                int a = FAST ? (aB + i * XSTR) : aS[i];
                v2f t; t.x = xs[a]; t.y = xs[a + 1];
                q[i] = t;
            }
#pragma unroll
            for (int i = 0; i < 17; ++i) {
                v2f uu; uu.x = u[i]; uu.y = u[i];
                v2f d = uu - q[i];
                q[i] = d * d;
            }
            v2f s[11];
            s[0] = ((q[0] + q[1]) + (q[2] + q[3])) + ((q[4] + q[5]) + q[6]);
#pragma unroll
            for (int k = 1; k < 11; ++k)
                s[k] = s[k - 1] + (q[k + 6] - q[k - 1]);
#pragma unroll
            for (int k = 0; k < 11; ++k)
                vo[k] = s[k];        // consecutive slots; slot 32 junk (g=2)
            if constexpr (FAST) {
                aB += 2;
            } else {
#pragma unroll
                for (int i = 0; i < 17; ++i) aS[i] += 2;
            }
        }
    };

    // scalar round: single offset (ox=20), then advance to next row.
    auto bv_single = [&](int buf) {
        if (bv) {
            v2f* vo = vsh + buf * VS_SZ + wb;
            float q[17];
#pragma unroll
            for (int i = 0; i < 17; ++i)
                q[i] = xs[FAST ? (aB + i * XSTR) : aS[i]];
#pragma unroll
            for (int i = 0; i < 17; ++i) {
                float d = u[i] - q[i];
                q[i] = d * d;
            }
            float s[11];
            s[0] = ((q[0] + q[1]) + (q[2] + q[3])) + ((q[4] + q[5]) + q[6]);
#pragma unroll
            for (int k = 1; k < 11; ++k)
                s[k] = s[k - 1] + (q[k + 6] - q[k - 1]);
#pragma unroll
            for (int k = 0; k < 11; ++k) {
                v2f t; t.x = s[k]; t.y = 0.0f;
                vo[k] = t;           // C single reads .x only
            }
            if constexpr (FAST) {
                aB += XSTR - 20;
            } else {
#pragma unroll
                for (int i = 0; i < 17; ++i) aS[i] += XSTR - 20;
            }
        }
    };

    auto c_pair = [&](int buf) {
        if (cact) {
            const v2f* vp = vsh + buf * VS_SZ + vb;
            v2f v0  = vp[0],       v1  = vp[VT],      v2  = vp[2 * VT];
            v2f v3  = vp[3 * VT],  v4  = vp[4 * VT],  v5  = vp[5 * VT];
            v2f v6  = vp[6 * VT],  v7  = vp[7 * VT],  v8  = vp[8 * VT];
            v2f v9  = vp[9 * VT],  v10 = vp[10 * VT], v11 = vp[11 * VT];
            v2f v12 = vp[12 * VT], v13 = vp[13 * VT];
            // chain for offset ox (x) and ox+1 (y), independent ILP streams
            v2f h0 = ((v0 + v1) + (v2 + v3)) + ((v4 + v5) + v6);
            v2f h1 = h0 - v0 + v7;
            v2f h2 = h1 - v1 + v8;
            v2f h3 = h2 - v2 + v9;
            v2f h4 = h3 - v3 + v10;
            v2f h5 = h4 - v4 + v11;
            v2f h6 = h5 - v5 + v12;
            v2f h7 = h6 - v6 + v13;
            float mx = fminf(fminf(fminf(h0.x, h1.x), fminf(h2.x, h3.x)),
                             fminf(fminf(h4.x, h5.x), fminf(h6.x, h7.x)));
            if (__builtin_expect(__ballot(mx <= HSKIP) != 0ull, 0)) {
                const int sp = svC + oxC;
                float w;
                w = __builtin_amdgcn_exp2f(h0.x * K); ws[0] += w; ac[0] = fmaf(w, xs[sp],     ac[0]);
                w = __builtin_amdgcn_exp2f(h1.x * K); ws[1] += w; ac[1] = fmaf(w, xs[sp + 1], ac[1]);
                w = __builtin_amdgcn_exp2f(h2.x * K); ws[2] += w; ac[2] = fmaf(w, xs[sp + 2], ac[2]);
                w = __builtin_amdgcn_exp2f(h3.x * K); ws[3] += w; ac[3] = fmaf(w, xs[sp + 3], ac[3]);
                w = __builtin_amdgcn_exp2f(h4.x * K); ws[4] += w; ac[4] = fmaf(w, xs[sp + 4], ac[4]);
                w = __builtin_amdgcn_exp2f(h5.x * K); ws[5] += w; ac[5] = fmaf(w, xs[sp + 5], ac[5]);
                w = __builtin_amdgcn_exp2f(h6.x * K); ws[6] += w; ac[6] = fmaf(w, xs[sp + 6], ac[6]);
                w = __builtin_amdgcn_exp2f(h7.x * K); ws[7] += w; ac[7] = fmaf(w, xs[sp + 7], ac[7]);
            }
            float my_ = fminf(fminf(fminf(h0.y, h1.y), fminf(h2.y, h3.y)),
                              fminf(fminf(h4.y, h5.y), fminf(h6.y, h7.y)));
            if (__builtin_expect(__ballot(my_ <= HSKIP) != 0ull, 0)) {
                const int sp = svC + oxC + 1;
                float w;
                w = __builtin_amdgcn_exp2f(h0.y * K); ws[0] += w; ac[0] = fmaf(w, xs[sp],     ac[0]);
                w = __builtin_amdgcn_exp2f(h1.y * K); ws[1] += w; ac[1] = fmaf(w, xs[sp + 1], ac[1]);
                w = __builtin_amdgcn_exp2f(h2.y * K); ws[2] += w; ac[2] = fmaf(w, xs[sp + 2], ac[2]);
                w = __builtin_amdgcn_exp2f(h3.y * K); ws[3] += w; ac[3] = fmaf(w, xs[sp + 3], ac[3]);
                w = __builtin_amdgcn_exp2f(h4.y * K); ws[4] += w; ac[4] = fmaf(w, xs[sp + 4], ac[4]);
                w = __builtin_amdgcn_exp2f(h5.y * K); ws[5] += w; ac[5] = fmaf(w, xs[sp + 5], ac[5]);
                w = __builtin_amdgcn_exp2f(h6.y * K); ws[6] += w; ac[6] = fmaf(w, xs[sp + 6], ac[6]);
                w = __builtin_amdgcn_exp2f(h7.y * K); ws[7] += w; ac[7] = fmaf(w, xs[sp + 7], ac[7]);
            }
        }
        oxC += 2;
    };

    auto c_single = [&](int buf) {
        if (cact) {
            const v2f* vp = vsh + buf * VS_SZ + vb;
            float v0  = vp[0].x,       v1  = vp[VT].x,      v2  = vp[2 * VT].x;
            float v3  = vp[3 * VT].x,  v4  = vp[4 * VT].x,  v5  = vp[5 * VT].x;
            float v6  = vp[6 * VT].x,  v7  = vp[7 * VT].x,  v8  = vp[8 * VT].x;
            float v9  = vp[9 * VT].x,  v10 = vp[10 * VT].x, v11 = vp[11 * VT].x;
            float v12 = vp[12 * VT].x, v13 = vp[13 * VT].x;
            float h0 = ((v0 + v1) + (v2 + v3)) + ((v4 + v5) + v6);
            float h1 = h0 - v0 + v7;
            float h2 = h1 - v1 + v8;
            float h3 = h2 - v2 + v9;
            float h4 = h3 - v3 + v10;
            float h5 = h4 - v4 + v11;
            float h6 = h5 - v5 + v12;
            float h7 = h6 - v6 + v13;
            float m = fminf(fminf(fminf(h0, h1), fminf(h2, h3)),
                            fminf(fminf(h4, h5), fminf(h6, h7)));
            if (__builtin_expect(__ballot(m <= HSKIP) != 0ull, 0)) {
                const int sp = svC + oxC;
                float w;
                w = __builtin_amdgcn_exp2f(h0 * K); ws[0] += w; ac[0] = fmaf(w, xs[sp],     ac[0]);
                w = __builtin_amdgcn_exp2f(h1 * K); ws[1] += w; ac[1] = fmaf(w, xs[sp + 1], ac[1]);
                w = __builtin_amdgcn_exp2f(h2 * K); ws[2] += w; ac[2] = fmaf(w, xs[sp + 2], ac[2]);
                w = __builtin_amdgcn_exp2f(h3 * K); ws[3] += w; ac[3] = fmaf(w, xs[sp + 3], ac[3]);
                w = __builtin_amdgcn_exp2f(h4 * K); ws[4] += w; ac[4] = fmaf(w, xs[sp + 4], ac[4]);
                w = __builtin_amdgcn_exp2f(h5 * K); ws[5] += w; ac[5] = fmaf(w, xs[sp + 5], ac[5]);
                w = __builtin_amdgcn_exp2f(h6 * K); ws[6] += w; ac[6] = fmaf(w, xs[sp + 6], ac[6]);
                w = __builtin_amdgcn_exp2f(h7 * K); ws[7] += w; ac[7] = fmaf(w, xs[sp + 7], ac[7]);
            }
        }
        oxC = 0; svC += XSTR;
    };

    // ---- round loop: 231 rounds (10 pair + 1 single per oy row) ----
    // Round r produces into buf r&1; C consumes round r-1 from buf 1-(r&1).
    // type(r) = (r%11==10) ? single : pair. Hazards: producer and consumer
    // always touch different buffers; buffer reuse separated by a barrier.
    bv_pair(0);
    __syncthreads();
#pragma unroll 1
    for (int r = 1; r < 231; ++r) {
        int m  = r % 11;
        int pm = (r - 1) % 11;
        if (m == 10) bv_single(r & 1); else bv_pair(r & 1);
        if (pm == 10) c_single(1 - (r & 1)); else c_pair(1 - (r & 1));
        __syncthreads();
    }
    c_single(0);   // round 230 (offset 440) lives in buffer 0

    if (cact) {
        float4 oA, oB;
        oA.x = fminf(fmaxf(ac[0] * __builtin_amdgcn_rcpf(ws[0]), 0.f), 1.f);
        oA.y = fminf(fmaxf(ac[1] * __builtin_amdgcn_rcpf(ws[1]), 0.f), 1.f);
        oA.z = fminf(fmaxf(ac[2] * __builtin_amdgcn_rcpf(ws[2]), 0.f), 1.f);
        oA.w = fminf(fmaxf(ac[3] * __builtin_amdgcn_rcpf(ws[3]), 0.f), 1.f);
        oB.x = fminf(fmaxf(ac[4] * __builtin_amdgcn_rcpf(ws[4]), 0.f), 1.f);
        oB.y = fminf(fmaxf(ac[5] * __builtin_amdgcn_rcpf(ws[5]), 0.f), 1.f);
        oB.z = fminf(fmaxf(ac[6] * __builtin_amdgcn_rcpf(ws[6]), 0.f), 1.f);
        oB.w = fminf(fmaxf(ac[7] * __builtin_amdgcn_rcpf(ws[7]), 0.f), 1.f);
        float* op = &out[((size_t)blockIdx.z * H + (gy0 + py)) * W + (gx0 + c8)];
        *reinterpret_cast<float4*>(op)     = oA;
        *reinterpret_cast<float4*>(op + 4) = oB;
    }
}

__global__ __launch_bounds__(256)
void nlm_kernel(const float* __restrict__ img_all, float* __restrict__ out,
                int H, int W) {
    __shared__ __align__(16) float xs[XSZ];
    __shared__ __align__(16) v2f vsh[2 * VS_SZ];
    const int tid = threadIdx.x;
    const int gx0 = blockIdx.x * TS;
    const int gy0 = blockIdx.y * TS;
    const float* img = img_all + (size_t)blockIdx.z * H * W;
    // FAST iff no patch-center row (gy0-3..gy0+35) folds at a y-edge.
    if (gy0 - 3 >= 0 && gy0 + 35 < H)
        nlm_body<true>(img, out, H, W, gx0, gy0, xs, vsh, tid);
    else
        nlm_body<false>(img, out, H, W, gx0, gy0, xs, vsh, tid);
}

extern "C" void kernel_launch(void* const* d_in, const int* in_sizes, int n_in,
                              void* d_out, int out_size, void* d_ws, size_t ws_size,
                              hipStream_t stream) {
    const float* x = (const float*)d_in[0];
    float* out = (float*)d_out;
    const int H = 1024, W = 1024;
    const int B = in_sizes[0] / (H * W);
    dim3 grid(W / TS, H / TS, B);
    nlm_kernel<<<grid, dim3(256), 0, stream>>>(x, out, H, W);
}